// Round 4
// baseline (311.931 us; speedup 1.0000x reference)
//
#include <hip/hip_runtime.h>
#include <cstdint>
#include <cstddef>

// Problem constants
constexpr int DD = 1024;        // D
constexpr int TT = 4096;        // T
constexpr int BB = 4;           // B
constexpr int MM = BB * TT;     // 16384 rows

typedef __bf16 bf16x8 __attribute__((ext_vector_type(8)));
typedef float  f32x16 __attribute__((ext_vector_type(16)));

__device__ __forceinline__ unsigned short f2bf(float f) {
  union { float f; uint32_t u; } c; c.f = f;
  uint32_t r = (c.u + 0x7FFFu + ((c.u >> 16) & 1u)) >> 16;
  return (unsigned short)r;
}

__device__ __forceinline__ float fast_rcp(float x) {
  return __builtin_amdgcn_rcpf(x);
}

// async global->LDS 16B per lane; lds_dst must be wave-uniform (HW adds lane*16)
__device__ __forceinline__ void async_ld16(const unsigned short* g, unsigned short* lds_dst) {
  __builtin_amdgcn_global_load_lds(
      (const __attribute__((address_space(1))) void*)g,
      (__attribute__((address_space(3))) void*)lds_dst,
      16, 0, 0);
}

// XOR-swizzled LDS tile layout: 16B slots, 2 global rows per 128B LDS line.
// slot(r,c) for global (row r, 16B-chunk c of a 64B/K=32 row panel).
__device__ __forceinline__ int lds_slot(int r, int c) {
  return ((r >> 1) << 3) + ((((r & 1) << 2) | c) ^ ((r >> 1) & 7));
}
// inverse: physical slot p -> (global row r, chunk c)
__device__ __forceinline__ void slot_decode(int p, int& r, int& c) {
  int L = p >> 3, u = (p & 7) ^ (L & 7);
  r = (L << 1) | (u >> 2);
  c = u & 3;
}

// ---------------------------------------------------------------------------
// Merged prep: blocks [0,1024) fold time-mix into weights (wave per row) and
// accumulate bias dots; blocks [1024, 1024+16384) convert x to bf16 and emit
// x[:, T-1, :].
__global__ void prep_all(const float* __restrict__ Wk, const float* __restrict__ Wv,
                         const float* __restrict__ Wr, const float* __restrict__ Wo,
                         const float* __restrict__ tmk, const float* __restrict__ tmv,
                         const float* __restrict__ tmr,
                         const float* __restrict__ last_x,
                         const float4* __restrict__ x,
                         unsigned short* __restrict__ wz,   // [3][1024][1024] bf16
                         unsigned short* __restrict__ wo,   // [1024][1024] bf16
                         float* __restrict__ bias,          // [3][1024]
                         ushort4* __restrict__ xb,          // [16384][1024] bf16
                         float4* __restrict__ out_xlast) {
  if (blockIdx.x < 1024) {
    int w = (blockIdx.x * 256 + threadIdx.x) >> 6;   // 0..4095
    int lane = threadIdx.x & 63;
    int z = w >> 10;           // 0..3
    int e = w & (DD - 1);
    const float* W  = (z == 0) ? Wk  : (z == 1) ? Wv  : (z == 2) ? Wr : Wo;
    const float* tm = (z == 0) ? tmk : (z == 1) ? tmv : tmr;
    unsigned short* dst = (z < 3) ? (wz + (size_t)z * DD * DD + (size_t)e * DD)
                                  : (wo + (size_t)e * DD);
    float s = 0.f;
#pragma unroll
    for (int j = 0; j < 4; ++j) {
      int d = j * 256 + lane * 4;
      float4 wv4 = *(const float4*)(W + (size_t)e * DD + d);
      if (z < 3) {
        float4 t4 = *(const float4*)(tm + d);
        float4 l4 = *(const float4*)(last_x + d);
        s += l4.x * (1.f - t4.x) * wv4.x + l4.y * (1.f - t4.y) * wv4.y +
             l4.z * (1.f - t4.z) * wv4.z + l4.w * (1.f - t4.w) * wv4.w;
        wv4.x *= t4.x; wv4.y *= t4.y; wv4.z *= t4.z; wv4.w *= t4.w;
      }
      ushort4 o;
      o.x = f2bf(wv4.x); o.y = f2bf(wv4.y); o.z = f2bf(wv4.z); o.w = f2bf(wv4.w);
      *(ushort4*)(dst + d) = o;
    }
    if (z < 3) {
      for (int off = 32; off; off >>= 1) s += __shfl_down(s, off, 64);
      if (lane == 0) bias[z * DD + e] = s;
    }
  } else {
    int i = (blockIdx.x - 1024) * 256 + threadIdx.x;  // < MM*DD/4
    float4 v = x[i];
    ushort4 o;
    o.x = f2bf(v.x); o.y = f2bf(v.y); o.z = f2bf(v.z); o.w = f2bf(v.w);
    xb[i] = o;
    int m = i >> 8;                                    // 256 float4 per row
    if ((m & (TT - 1)) == (TT - 1)) {
      int b = m >> 12;
      out_xlast[b * 256 + (i & 255)] = v;
    }
  }
}

// ---------------------------------------------------------------------------
// Fused GEMM1 + WKV. 32x32x16 MFMA, swizzled LDS, BK=64 two-panel.
// Block: 256 thr (4 waves, 2m x 2n). Tile: M=128, N=64 per zone, 3 zones.
// Wave tile: 64m x 32n per zone -> acc[3][2] of f32x16.
__global__ __launch_bounds__(256, 2) void gemm_kvr(
    const unsigned short* __restrict__ A,     // [16384][1024] bf16
    const unsigned short* __restrict__ Wz,    // [3][1024][1024] bf16
    const float* __restrict__ bias,           // [3][1024]
    const float* __restrict__ time_first, const float* __restrict__ time_decay,
    const float* __restrict__ last_num, const float* __restrict__ last_den,
    unsigned short* __restrict__ rwkv,        // [16384][1024] bf16
    float* __restrict__ out_num, float* __restrict__ out_den) {
  __shared__ unsigned short lA[2][128 * 32];
  __shared__ unsigned short lB[2][3][64 * 32];
  const int tid  = threadIdx.x;
  const int lane = tid & 63;
  const int wave = tid >> 6;
  const int n0 = blockIdx.x * 64;    // zone-local col base
  const int m0 = blockIdx.y * 128;
  const int wm = (wave >> 1) * 64;
  const int wn = (wave & 1) * 32;

  f32x16 acc[3][2] = {};

  const int l31 = lane & 31;
  const int lhi = lane >> 5;         // 0/1 -> k-half within K16

  // staging decode (same for both A issues and B)
  int srA0, scA0, srA1, scA1, srB, scB;
  slot_decode(tid,       srA0, scA0);
  slot_decode(256 + tid, srA1, scA1);
  slot_decode(tid,       srB,  scB);   // 256 slots = 64 rows

  for (int k0 = 0; k0 < DD; k0 += 64) {
    __syncthreads();
#pragma unroll
    for (int h = 0; h < 2; ++h) {
      int kk = k0 + h * 32;
      async_ld16(A + (size_t)(m0 + srA0) * DD + (kk + scA0 * 8),
                 lA[h] + (size_t)(wave * 64) * 8);
      async_ld16(A + (size_t)(m0 + srA1) * DD + (kk + scA1 * 8),
                 lA[h] + (size_t)(256 + wave * 64) * 8);
#pragma unroll
      for (int z = 0; z < 3; ++z) {
        async_ld16(Wz + (size_t)z * DD * DD + (size_t)(n0 + srB) * DD + (kk + scB * 8),
                   lB[h][z] + (size_t)(wave * 64) * 8);
      }
    }
    __syncthreads();

#pragma unroll
    for (int h = 0; h < 2; ++h) {
#pragma unroll
      for (int h16 = 0; h16 < 2; ++h16) {
        int cc = h16 * 2 + lhi;      // 16B chunk within K32 panel
        bf16x8 af[2], bz[3];
#pragma unroll
        for (int mi = 0; mi < 2; ++mi)
          af[mi] = *(const bf16x8*)(lA[h] + (size_t)lds_slot(wm + mi * 32 + l31, cc) * 8);
#pragma unroll
        for (int z = 0; z < 3; ++z)
          bz[z] = *(const bf16x8*)(lB[h][z] + (size_t)lds_slot(wn + l31, cc) * 8);
#pragma unroll
        for (int z = 0; z < 3; ++z)
#pragma unroll
          for (int mi = 0; mi < 2; ++mi)
            acc[z][mi] = __builtin_amdgcn_mfma_f32_32x32x16_bf16(
                af[mi], bz[z], acc[z][mi], 0, 0, 0);
      }
    }
  }

  // Epilogue. 32x32 C/D: col = lane&31, row = (reg&3) + 8*(reg>>2) + 4*(lane>>5).
  const int gnz = n0 + wn + l31;
  const float bk = bias[gnz], bv = bias[DD + gnz], br = bias[2 * DD + gnz];
  const float tf = time_first[gnz];
  const float ln = last_num[gnz], ld = last_den[gnz];
  const int rbase = 4 * lhi;
#pragma unroll
  for (int mi = 0; mi < 2; ++mi) {
#pragma unroll
    for (int reg = 0; reg < 16; ++reg) {
      int row = (reg & 3) + 8 * (reg >> 2) + rbase;
      int gm = m0 + wm + mi * 32 + row;
      float kk = acc[0][mi][reg] + bk;
      float vv = acc[1][mi][reg] + bv;
      float rr = acc[2][mi][reg] + br;
      float efk = __expf(tf + kk);
      float wkv = (ln + efk * vv) * fast_rcp(ld + efk);
      float sr  = fast_rcp(1.0f + __expf(-rr));
      rwkv[(size_t)gm * DD + gnz] = f2bf(sr * wkv);
      if ((gm & (TT - 1)) == (TT - 1)) {
        int b = gm >> 12;
        float dec = __expf(-__expf(time_decay[gnz]));
        float ek  = __expf(kk);
        out_num[b * DD + gnz] = dec * ln + ek * vv;
        out_den[b * DD + gnz] = dec * ld + ek;
      }
    }
  }
}

// ---------------------------------------------------------------------------
// GEMM2: C[M,N] = A[M,K] @ B[N,K]^T, fp32 out. 32x32x16 MFMA, swizzled LDS,
// BK=64 two-panel. Wave tile 64x64 -> acc[2][2] of f32x16.
__global__ void gemm_bt128(const unsigned short* __restrict__ A,
                           const unsigned short* __restrict__ Bw,
                           float* __restrict__ Cf,
                           int M, int N, int K) {
  __shared__ unsigned short lA[2][128 * 32];
  __shared__ unsigned short lB[2][128 * 32];
  const int tid  = threadIdx.x;
  const int lane = tid & 63;
  const int wave = tid >> 6;
  const int n0 = blockIdx.x * 128;
  const int m0 = blockIdx.y * 128;
  const int wm = (wave >> 1) * 64;
  const int wn = (wave & 1) * 64;

  f32x16 acc[2][2] = {};
  const int l31 = lane & 31;
  const int lhi = lane >> 5;

  int sr0, sc0, sr1, sc1;
  slot_decode(tid,       sr0, sc0);
  slot_decode(256 + tid, sr1, sc1);

  for (int k0 = 0; k0 < K; k0 += 64) {
    __syncthreads();
#pragma unroll
    for (int h = 0; h < 2; ++h) {
      int kk = k0 + h * 32;
      async_ld16(A + (size_t)(m0 + sr0) * K + (kk + sc0 * 8),
                 lA[h] + (size_t)(wave * 64) * 8);
      async_ld16(A + (size_t)(m0 + sr1) * K + (kk + sc1 * 8),
                 lA[h] + (size_t)(256 + wave * 64) * 8);
      async_ld16(Bw + (size_t)(n0 + sr0) * K + (kk + sc0 * 8),
                 lB[h] + (size_t)(wave * 64) * 8);
      async_ld16(Bw + (size_t)(n0 + sr1) * K + (kk + sc1 * 8),
                 lB[h] + (size_t)(256 + wave * 64) * 8);
    }
    __syncthreads();

#pragma unroll
    for (int h = 0; h < 2; ++h) {
#pragma unroll
      for (int h16 = 0; h16 < 2; ++h16) {
        int cc = h16 * 2 + lhi;
        bf16x8 af[2], bf[2];
#pragma unroll
        for (int i = 0; i < 2; ++i) {
          af[i] = *(const bf16x8*)(lA[h] + (size_t)lds_slot(wm + i * 32 + l31, cc) * 8);
          bf[i] = *(const bf16x8*)(lB[h] + (size_t)lds_slot(wn + i * 32 + l31, cc) * 8);
        }
#pragma unroll
        for (int mi = 0; mi < 2; ++mi)
#pragma unroll
          for (int ni = 0; ni < 2; ++ni)
            acc[mi][ni] = __builtin_amdgcn_mfma_f32_32x32x16_bf16(
                af[mi], bf[ni], acc[mi][ni], 0, 0, 0);
      }
    }
  }

  const int rbase = 4 * lhi;
#pragma unroll
  for (int mi = 0; mi < 2; ++mi) {
#pragma unroll
    for (int ni = 0; ni < 2; ++ni) {
      int gn = n0 + wn + ni * 32 + l31;
#pragma unroll
      for (int reg = 0; reg < 16; ++reg) {
        int row = (reg & 3) + 8 * (reg >> 2) + rbase;
        int gm = m0 + wm + mi * 32 + row;
        Cf[(size_t)gm * N + gn] = acc[mi][ni][reg];
      }
    }
  }
}

// ---------------------------------------------------------------------------
extern "C" void kernel_launch(void* const* d_in, const int* in_sizes, int n_in,
                              void* d_out, int out_size, void* d_ws, size_t ws_size,
                              hipStream_t stream) {
  const float* x          = (const float*)d_in[0];
  const float* last_x     = (const float*)d_in[1];
  const float* last_num   = (const float*)d_in[2];
  const float* last_den   = (const float*)d_in[3];
  const float* time_decay = (const float*)d_in[4];
  const float* time_first = (const float*)d_in[5];
  const float* tmk        = (const float*)d_in[6];
  const float* tmv        = (const float*)d_in[7];
  const float* tmr        = (const float*)d_in[8];
  const float* Wk         = (const float*)d_in[9];
  const float* Wv         = (const float*)d_in[10];
  const float* Wr         = (const float*)d_in[11];
  const float* Wo         = (const float*)d_in[12];

  float* out       = (float*)d_out;                  // [MM][DD]
  float* out_xlast = out + (size_t)MM * DD;          // [BB][DD]
  float* out_num   = out_xlast + BB * DD;            // [BB][DD]
  float* out_den   = out_num + BB * DD;              // [BB][DD]

  char* ws = (char*)d_ws;
  unsigned short* xb   = (unsigned short*)ws;                 // 33,554,432 B
  unsigned short* wz   = (unsigned short*)(ws + 33554432);    //  6,291,456 B
  unsigned short* wo   = (unsigned short*)(ws + 39845888);    //  2,097,152 B
  float*          bias = (float*)(ws + 41943040);             //     12,288 B
  unsigned short* rwkv = (unsigned short*)(ws + 41955328);    // 33,554,432 B (no alias with xb)

  prep_all<<<1024 + MM * DD / 4 / 256, 256, 0, stream>>>(
      Wk, Wv, Wr, Wo, tmk, tmv, tmr, last_x, (const float4*)x,
      wz, wo, bias, (ushort4*)xb, (float4*)out_xlast);

  // Fused: kvr GEMM + WKV -> rwkv [16384, 1024], plus num/den state rows
  gemm_kvr<<<dim3(DD / 64, MM / 128), 256, 0, stream>>>(
      xb, wz, bias, time_first, time_decay, last_num, last_den,
      rwkv, out_num, out_den);

  // out = rwkv @ wo^T : [16384, 1024]
  gemm_bt128<<<dim3(DD / 128, MM / 128), 256, 0, stream>>>(
      rwkv, wo, out, MM, DD, DD);
}

// Round 5
// 293.501 us; speedup vs baseline: 1.0628x; 1.0628x over previous
//
#include <hip/hip_runtime.h>
#include <cstdint>
#include <cstddef>

// Problem constants
constexpr int DD = 1024;        // D
constexpr int TT = 4096;        // T
constexpr int BB = 4;           // B
constexpr int MM = BB * TT;     // 16384 rows

typedef __bf16 bf16x8 __attribute__((ext_vector_type(8)));
typedef float  f32x4  __attribute__((ext_vector_type(4)));

__device__ __forceinline__ unsigned short f2bf(float f) {
  union { float f; uint32_t u; } c; c.f = f;
  uint32_t r = (c.u + 0x7FFFu + ((c.u >> 16) & 1u)) >> 16;
  return (unsigned short)r;
}

__device__ __forceinline__ float fast_rcp(float x) {
  return __builtin_amdgcn_rcpf(x);
}

// async global->LDS 16B per lane; lds_dst must be wave-uniform (HW adds lane*16)
__device__ __forceinline__ void async_ld16(const unsigned short* g, unsigned short* lds_dst) {
  __builtin_amdgcn_global_load_lds(
      (const __attribute__((address_space(1))) void*)g,
      (__attribute__((address_space(3))) void*)lds_dst,
      16, 0, 0);
}

// ---------------------------------------------------------------------------
// Merged prep: blocks [0,1024) fold time-mix into weights (wave per row) and
// accumulate bias dots; blocks [1024, 1024+16384) convert x to bf16 and emit
// x[:, T-1, :].
__global__ void prep_all(const float* __restrict__ Wk, const float* __restrict__ Wv,
                         const float* __restrict__ Wr, const float* __restrict__ Wo,
                         const float* __restrict__ tmk, const float* __restrict__ tmv,
                         const float* __restrict__ tmr,
                         const float* __restrict__ last_x,
                         const float4* __restrict__ x,
                         unsigned short* __restrict__ wz,   // [3][1024][1024] bf16
                         unsigned short* __restrict__ wo,   // [1024][1024] bf16
                         float* __restrict__ bias,          // [3][1024]
                         ushort4* __restrict__ xb,          // [16384][1024] bf16
                         float4* __restrict__ out_xlast) {
  if (blockIdx.x < 1024) {
    int w = (blockIdx.x * 256 + threadIdx.x) >> 6;   // 0..4095
    int lane = threadIdx.x & 63;
    int z = w >> 10;           // 0..3
    int e = w & (DD - 1);
    const float* W  = (z == 0) ? Wk  : (z == 1) ? Wv  : (z == 2) ? Wr : Wo;
    const float* tm = (z == 0) ? tmk : (z == 1) ? tmv : tmr;
    unsigned short* dst = (z < 3) ? (wz + (size_t)z * DD * DD + (size_t)e * DD)
                                  : (wo + (size_t)e * DD);
    float s = 0.f;
#pragma unroll
    for (int j = 0; j < 4; ++j) {
      int d = j * 256 + lane * 4;
      float4 wv4 = *(const float4*)(W + (size_t)e * DD + d);
      if (z < 3) {
        float4 t4 = *(const float4*)(tm + d);
        float4 l4 = *(const float4*)(last_x + d);
        s += l4.x * (1.f - t4.x) * wv4.x + l4.y * (1.f - t4.y) * wv4.y +
             l4.z * (1.f - t4.z) * wv4.z + l4.w * (1.f - t4.w) * wv4.w;
        wv4.x *= t4.x; wv4.y *= t4.y; wv4.z *= t4.z; wv4.w *= t4.w;
      }
      ushort4 o;
      o.x = f2bf(wv4.x); o.y = f2bf(wv4.y); o.z = f2bf(wv4.z); o.w = f2bf(wv4.w);
      *(ushort4*)(dst + d) = o;
    }
    if (z < 3) {
      for (int off = 32; off; off >>= 1) s += __shfl_down(s, off, 64);
      if (lane == 0) bias[z * DD + e] = s;
    }
  } else {
    int i = (blockIdx.x - 1024) * 256 + threadIdx.x;  // < MM*DD/4
    float4 v = x[i];
    ushort4 o;
    o.x = f2bf(v.x); o.y = f2bf(v.y); o.z = f2bf(v.z); o.w = f2bf(v.w);
    xb[i] = o;
    int m = i >> 8;                                    // 256 float4 per row
    if ((m & (TT - 1)) == (TT - 1)) {
      int b = m >> 12;
      out_xlast[b * 256 + (i & 255)] = v;
    }
  }
}

// ---------------------------------------------------------------------------
// Fused GEMM1 + WKV, two-panel BK=64, 16x16x32 MFMA, linear LDS (R3 structure).
// XCD-locality swizzle: id&7 selects XCD-owned m-super-stripe; n iterates
// fastest so one A-stripe stays hot in a single XCD's L2 across its 16
// n-consumers.
__global__ __launch_bounds__(256, 2) void gemm_kvr(
    const unsigned short* __restrict__ A,     // [16384][1024] bf16
    const unsigned short* __restrict__ Wz,    // [3][1024][1024] bf16
    const float* __restrict__ bias,           // [3][1024]
    const float* __restrict__ time_first, const float* __restrict__ time_decay,
    const float* __restrict__ last_num, const float* __restrict__ last_den,
    unsigned short* __restrict__ rwkv,        // [16384][1024] bf16
    float* __restrict__ out_num, float* __restrict__ out_den) {
  __shared__ unsigned short lA[2][128 * 32];
  __shared__ unsigned short lB[2][3][64 * 32];
  const int tid  = threadIdx.x;
  const int lane = tid & 63;
  const int wave = tid >> 6;

  // XCD-aware remap of (n0, m0). Grid: 16 x 128 = 2048 blocks.
  const int id  = blockIdx.y * gridDim.x + blockIdx.x;   // 0..2047
  const int xcd = id & 7;
  const int s   = id >> 3;                               // 0..255
  const int m0 = (xcd * 16 + (s >> 4)) * 128;            // m-stripe
  const int n0 = (s & 15) * 64;                          // zone-local col base

  const int wm = (wave >> 1) * 64;
  const int wn = (wave & 1) * 32;

  f32x4 acc[3][4][2] = {};

  const int fr_row = lane & 15;
  const int fr_kb  = (lane >> 4) * 16;   // byte offset within row (8 bf16)
  const int srow = tid >> 2;             // staging row (0..63)
  const int scol = (tid & 3) * 8;        // staging col (bf16 elems)

  for (int k0 = 0; k0 < DD; k0 += 64) {
    __syncthreads();
#pragma unroll
    for (int h = 0; h < 2; ++h) {
      int kk = k0 + h * 32;
#pragma unroll
      for (int it = 0; it < 2; ++it) {
        int cc  = it * 256 + tid;
        int row = cc >> 2;
        async_ld16(A + (size_t)(m0 + row) * DD + (kk + scol),
                   lA[h] + (size_t)(it * 256 + wave * 64) * 8);
      }
#pragma unroll
      for (int z = 0; z < 3; ++z) {
        async_ld16(Wz + (size_t)z * DD * DD + (size_t)(n0 + srow) * DD + (kk + scol),
                   lB[h][z] + (size_t)(wave * 64) * 8);
      }
    }
    __syncthreads();

#pragma unroll
    for (int h = 0; h < 2; ++h) {
      bf16x8 af[4], bfr[3][2];
#pragma unroll
      for (int i = 0; i < 4; ++i)
        af[i] = *(const bf16x8*)((const char*)lA[h] + ((wm + i * 16 + fr_row) * 64 + fr_kb));
#pragma unroll
      for (int z = 0; z < 3; ++z)
#pragma unroll
        for (int j = 0; j < 2; ++j)
          bfr[z][j] = *(const bf16x8*)((const char*)lB[h][z] + ((wn + j * 16 + fr_row) * 64 + fr_kb));

#pragma unroll
      for (int mi = 0; mi < 4; ++mi)
#pragma unroll
        for (int z = 0; z < 3; ++z)
#pragma unroll
          for (int ni = 0; ni < 2; ++ni)
            acc[z][mi][ni] = __builtin_amdgcn_mfma_f32_16x16x32_bf16(
                af[mi], bfr[z][ni], acc[z][mi][ni], 0, 0, 0);
    }
  }

  // Epilogue: WKV in-register. C/D layout: col = lane&15, row = (lane>>4)*4 + reg.
  const int crow = (lane >> 4) * 4;
  const int ccol = lane & 15;
#pragma unroll
  for (int ni = 0; ni < 2; ++ni) {
    int gnz = n0 + wn + ni * 16 + ccol;   // zone-local channel d
    float bk = bias[gnz], bv = bias[DD + gnz], br = bias[2 * DD + gnz];
    float tf = time_first[gnz];
    float ln = last_num[gnz], ld = last_den[gnz];
    float dec = __expf(-__expf(time_decay[gnz]));   // hoisted
#pragma unroll
    for (int mi = 0; mi < 4; ++mi) {
#pragma unroll
      for (int r = 0; r < 4; ++r) {
        int gm = m0 + wm + mi * 16 + crow + r;
        float kk = acc[0][mi][ni][r] + bk;
        float vv = acc[1][mi][ni][r] + bv;
        float rr = acc[2][mi][ni][r] + br;
        float efk = __expf(tf + kk);
        float wkv = (ln + efk * vv) * fast_rcp(ld + efk);
        float sr  = fast_rcp(1.0f + __expf(-rr));
        rwkv[(size_t)gm * DD + gnz] = f2bf(sr * wkv);
        if ((gm & (TT - 1)) == (TT - 1)) {
          int b = gm >> 12;
          float ek = __expf(kk);
          out_num[b * DD + gnz] = dec * ln + ek * vv;
          out_den[b * DD + gnz] = dec * ld + ek;
        }
      }
    }
  }
}

// ---------------------------------------------------------------------------
// GEMM2: C[M,N] = A[M,K] @ B[N,K]^T, fp32 out. Two-panel BK=64 (R3 structure)
// + XCD-locality swizzle.
__global__ void gemm_bt128(const unsigned short* __restrict__ A,
                           const unsigned short* __restrict__ Bw,
                           float* __restrict__ Cf,
                           int M, int N, int K) {
  __shared__ unsigned short lA[2][128 * 32];
  __shared__ unsigned short lB[2][128 * 32];
  const int tid  = threadIdx.x;
  const int lane = tid & 63;
  const int wave = tid >> 6;

  // XCD-aware remap: m-stripes partitioned across XCDs, n fastest.
  const int nBlocks = N >> 7;
  const int mBlocks = M >> 7;
  const int id  = blockIdx.y * gridDim.x + blockIdx.x;
  const int xcd = id & 7;
  const int s   = id >> 3;
  const int mPer = mBlocks >> 3;           // m-stripes per XCD (M=16384 -> 16)
  const int m0 = (xcd * mPer + s / nBlocks) * 128;
  const int n0 = (s % nBlocks) * 128;

  const int wm = (wave >> 1) * 64;
  const int wn = (wave & 1) * 64;

  f32x4 acc[4][4] = {};
  const int fr_row = lane & 15;
  const int fr_kb  = (lane >> 4) * 16;
  const int scol = (tid & 3) * 8;

  for (int k0 = 0; k0 < K; k0 += 64) {
    __syncthreads();
#pragma unroll
    for (int h = 0; h < 2; ++h) {
      int kk = k0 + h * 32;
#pragma unroll
      for (int it = 0; it < 2; ++it) {
        int cc  = it * 256 + tid;
        int row = cc >> 2;
        async_ld16(A + (size_t)(m0 + row) * K + (kk + scol),
                   lA[h] + (size_t)(it * 256 + wave * 64) * 8);
      }
#pragma unroll
      for (int it = 0; it < 2; ++it) {
        int cc  = it * 256 + tid;
        int row = cc >> 2;
        async_ld16(Bw + (size_t)(n0 + row) * K + (kk + scol),
                   lB[h] + (size_t)(it * 256 + wave * 64) * 8);
      }
    }
    __syncthreads();

#pragma unroll
    for (int h = 0; h < 2; ++h) {
      bf16x8 af[4], bfr[4];
#pragma unroll
      for (int i = 0; i < 4; ++i) {
        af[i]  = *(const bf16x8*)((const char*)lA[h] + ((wm + i * 16 + fr_row) * 64 + fr_kb));
        bfr[i] = *(const bf16x8*)((const char*)lB[h] + ((wn + i * 16 + fr_row) * 64 + fr_kb));
      }
#pragma unroll
      for (int mi = 0; mi < 4; ++mi)
#pragma unroll
        for (int ni = 0; ni < 4; ++ni)
          acc[mi][ni] = __builtin_amdgcn_mfma_f32_16x16x32_bf16(af[mi], bfr[ni], acc[mi][ni], 0, 0, 0);
    }
  }

  const int crow = (lane >> 4) * 4;
  const int ccol = lane & 15;
#pragma unroll
  for (int mi = 0; mi < 4; ++mi) {
#pragma unroll
    for (int ni = 0; ni < 4; ++ni) {
      int gn = n0 + wn + ni * 16 + ccol;
#pragma unroll
      for (int r = 0; r < 4; ++r) {
        int gm = m0 + wm + mi * 16 + crow + r;
        Cf[(size_t)gm * N + gn] = acc[mi][ni][r];
      }
    }
  }
}

// ---------------------------------------------------------------------------
extern "C" void kernel_launch(void* const* d_in, const int* in_sizes, int n_in,
                              void* d_out, int out_size, void* d_ws, size_t ws_size,
                              hipStream_t stream) {
  const float* x          = (const float*)d_in[0];
  const float* last_x     = (const float*)d_in[1];
  const float* last_num   = (const float*)d_in[2];
  const float* last_den   = (const float*)d_in[3];
  const float* time_decay = (const float*)d_in[4];
  const float* time_first = (const float*)d_in[5];
  const float* tmk        = (const float*)d_in[6];
  const float* tmv        = (const float*)d_in[7];
  const float* tmr        = (const float*)d_in[8];
  const float* Wk         = (const float*)d_in[9];
  const float* Wv         = (const float*)d_in[10];
  const float* Wr         = (const float*)d_in[11];
  const float* Wo         = (const float*)d_in[12];

  float* out       = (float*)d_out;                  // [MM][DD]
  float* out_xlast = out + (size_t)MM * DD;          // [BB][DD]
  float* out_num   = out_xlast + BB * DD;            // [BB][DD]
  float* out_den   = out_num + BB * DD;              // [BB][DD]

  char* ws = (char*)d_ws;
  unsigned short* xb   = (unsigned short*)ws;                 // 33,554,432 B
  unsigned short* wz   = (unsigned short*)(ws + 33554432);    //  6,291,456 B
  unsigned short* wo   = (unsigned short*)(ws + 39845888);    //  2,097,152 B
  float*          bias = (float*)(ws + 41943040);             //     12,288 B
  unsigned short* rwkv = (unsigned short*)(ws + 41955328);    // 33,554,432 B (no alias with xb)

  prep_all<<<1024 + MM * DD / 4 / 256, 256, 0, stream>>>(
      Wk, Wv, Wr, Wo, tmk, tmv, tmr, last_x, (const float4*)x,
      wz, wo, bias, (ushort4*)xb, (float4*)out_xlast);

  // Fused: kvr GEMM + WKV -> rwkv [16384, 1024], plus num/den state rows
  gemm_kvr<<<dim3(DD / 64, MM / 128), 256, 0, stream>>>(
      xb, wz, bias, time_first, time_decay, last_num, last_den,
      rwkv, out_num, out_den);

  // out = rwkv @ wo^T : [16384, 1024]
  gemm_bt128<<<dim3(DD / 128, MM / 128), 256, 0, stream>>>(
      rwkv, wo, out, MM, DD, DD);
}